// Round 1
// baseline (5822.897 us; speedup 1.0000x reference)
//
#include <hip/hip_runtime.h>

#define NN 100000
#define NE 1600000
#define NP 200000
#define CH 128

// ---- in-degree: one thread per edge ----
__global__ void degree_kernel(const int* __restrict__ dst, float* __restrict__ deg, int E) {
    int e = blockIdx.x * blockDim.x + threadIdx.x;
    if (e < E) atomicAdd(&deg[dst[e]], 1.0f);
}

// ---- scatter: 32 threads per edge, 4 channels each, float4 gather + 4 atomics ----
__global__ void scatter_kernel(const float* __restrict__ feat,
                               const int* __restrict__ src,
                               const int* __restrict__ dst,
                               const float* __restrict__ ew,
                               float* __restrict__ agg, int E) {
    long tid = (long)blockIdx.x * blockDim.x + threadIdx.x;
    int e = (int)(tid >> 5);
    if (e >= E) return;
    int c = (int)(tid & 31) << 2;
    int s = src[e], d = dst[e];
    float w = ew[e];
    float4 v = *(const float4*)&feat[(size_t)s * CH + c];
    float* o = &agg[(size_t)d * CH + c];
    atomicAdd(o + 0, v.x * w);
    atomicAdd(o + 1, v.y * w);
    atomicAdd(o + 2, v.z * w);
    atomicAdd(o + 3, v.w * w);
}

// ---- fused layer: out = (agg/deg)@w_rel + b + in@w_root  (optional relu) ----
// block = 256 threads, tile = 32 nodes x 128 outputs
// thread: jt = tid&31 -> 4 contiguous j's; nt = tid>>5 -> 4 nodes (nt*4..+3)
template <bool RELU>
__global__ __launch_bounds__(256)
void layer_kernel(const float* __restrict__ agg,
                  const float* __restrict__ deg,
                  const float* __restrict__ xin,
                  const float* __restrict__ w_rel,
                  const float* __restrict__ b_rel,
                  const float* __restrict__ w_root,
                  float* __restrict__ out, int N) {
    __shared__ float s_a[32][CH];
    __shared__ float s_x[32][CH];
    __shared__ float s_inv[32];

    const int nb = blockIdx.x * 32;
    const int tid = threadIdx.x;

    if (tid < 32) {
        int gn = nb + tid;
        float c = (gn < N) ? deg[gn] : 1.0f;
        s_inv[tid] = 1.0f / fmaxf(c, 1.0f);
    }
    __syncthreads();

    // stage 32 node rows of agg (x inv_deg) and xin into LDS
    for (int idx = tid; idx < 32 * 32; idx += 256) {
        int n = idx >> 5;
        int c = (idx & 31) << 2;
        int gn = nb + n;
        float4 a = make_float4(0.f, 0.f, 0.f, 0.f);
        float4 x = a;
        if (gn < N) {
            a = *(const float4*)&agg[(size_t)gn * CH + c];
            x = *(const float4*)&xin[(size_t)gn * CH + c];
        }
        float inv = s_inv[n];
        a.x *= inv; a.y *= inv; a.z *= inv; a.w *= inv;
        *(float4*)&s_a[n][c] = a;
        *(float4*)&s_x[n][c] = x;
    }
    __syncthreads();

    const int jt = tid & 31;
    const int j4 = jt << 2;
    const int n0 = (tid >> 5) << 2;   // 8 groups x 4 nodes

    float4 acc[4];
#pragma unroll
    for (int nn = 0; nn < 4; nn++) acc[nn] = make_float4(0.f, 0.f, 0.f, 0.f);

    for (int k0 = 0; k0 < CH; k0 += 4) {
        float4 a[4], x[4];
#pragma unroll
        for (int nn = 0; nn < 4; nn++) {
            a[nn] = *(const float4*)&s_a[n0 + nn][k0];
            x[nn] = *(const float4*)&s_x[n0 + nn][k0];
        }
#pragma unroll
        for (int kk = 0; kk < 4; kk++) {
            float4 wr = *(const float4*)&w_rel[(size_t)(k0 + kk) * CH + j4];
            float4 wo = *(const float4*)&w_root[(size_t)(k0 + kk) * CH + j4];
#pragma unroll
            for (int nn = 0; nn < 4; nn++) {
                float av = ((const float*)&a[nn])[kk];
                float xv = ((const float*)&x[nn])[kk];
                acc[nn].x += av * wr.x + xv * wo.x;
                acc[nn].y += av * wr.y + xv * wo.y;
                acc[nn].z += av * wr.z + xv * wo.z;
                acc[nn].w += av * wr.w + xv * wo.w;
            }
        }
    }

    float4 b4 = *(const float4*)&b_rel[j4];
#pragma unroll
    for (int nn = 0; nn < 4; nn++) {
        int gn = nb + n0 + nn;
        if (gn >= N) continue;
        float4 r;
        r.x = acc[nn].x + b4.x;
        r.y = acc[nn].y + b4.y;
        r.z = acc[nn].z + b4.z;
        r.w = acc[nn].w + b4.w;
        if (RELU) {
            r.x = fmaxf(r.x, 0.f); r.y = fmaxf(r.y, 0.f);
            r.z = fmaxf(r.z, 0.f); r.w = fmaxf(r.w, 0.f);
        }
        *(float4*)&out[(size_t)gn * CH + j4] = r;
    }
}

// ---- decode: one wave (64 lanes) per pair, float2 loads, shuffle reduce ----
__global__ void decode_kernel(const float* __restrict__ z,
                              const int* __restrict__ ps,
                              const int* __restrict__ pd,
                              float* __restrict__ out, int P) {
    long tid = (long)blockIdx.x * blockDim.x + threadIdx.x;
    int p = (int)(tid >> 6);
    int lane = (int)(tid & 63);
    if (p >= P) return;
    int s = ps[p], d = pd[p];
    float2 a = *(const float2*)&z[(size_t)s * CH + lane * 2];
    float2 b = *(const float2*)&z[(size_t)d * CH + lane * 2];
    float v = a.x * b.x + a.y * b.y;
#pragma unroll
    for (int off = 32; off > 0; off >>= 1) v += __shfl_down(v, off, 64);
    if (lane == 0) out[p] = v * 0.08838834764831845f;  // 1/sqrt(128)
}

extern "C" void kernel_launch(void* const* d_in, const int* in_sizes, int n_in,
                              void* d_out, int out_size, void* d_ws, size_t ws_size,
                              hipStream_t stream) {
    const float* x       = (const float*)d_in[0];
    const int*   ei      = (const int*)d_in[1];   // [2, E]: src then dst
    const float* ew      = (const float*)d_in[2];
    const int*   eli     = (const int*)d_in[3];   // [2, P]
    const float* w1_rel  = (const float*)d_in[4];
    const float* b1      = (const float*)d_in[5];
    const float* w1_root = (const float*)d_in[6];
    const float* w2_rel  = (const float*)d_in[7];
    const float* b2      = (const float*)d_in[8];
    const float* w2_root = (const float*)d_in[9];
    float* out = (float*)d_out;

    const int N = NN, E = NE, P = NP;
    const size_t rowbytes = (size_t)N * CH * sizeof(float);

    char* ws = (char*)d_ws;
    float* agg = (float*)(ws);
    float* h   = (float*)(ws + rowbytes);
    float* z   = (float*)(ws + 2 * rowbytes);
    float* deg = (float*)(ws + 3 * rowbytes);

    const int* src = ei;
    const int* dst = ei + E;

    // layer 1
    hipMemsetAsync(agg, 0, rowbytes, stream);
    hipMemsetAsync(deg, 0, (size_t)N * sizeof(float), stream);
    degree_kernel<<<(E + 255) / 256, 256, 0, stream>>>(dst, deg, E);
    {
        long threads = (long)E * 32;
        scatter_kernel<<<(int)((threads + 255) / 256), 256, 0, stream>>>(x, src, dst, ew, agg, E);
    }
    layer_kernel<true><<<(N + 31) / 32, 256, 0, stream>>>(agg, deg, x, w1_rel, b1, w1_root, h, N);

    // layer 2
    hipMemsetAsync(agg, 0, rowbytes, stream);
    {
        long threads = (long)E * 32;
        scatter_kernel<<<(int)((threads + 255) / 256), 256, 0, stream>>>(h, src, dst, ew, agg, E);
    }
    layer_kernel<false><<<(N + 31) / 32, 256, 0, stream>>>(agg, deg, h, w2_rel, b2, w2_root, z, N);

    // decode
    {
        long threads = (long)P * 64;
        decode_kernel<<<(int)((threads + 255) / 256), 256, 0, stream>>>(z, eli, eli + P, out, P);
    }
}

// Round 2
// 903.337 us; speedup vs baseline: 6.4460x; 6.4460x over previous
//
#include <hip/hip_runtime.h>

#define NN 100000
#define NE 1600000
#define NP 200000
#define CH 128
#define SB 1024   // scan block size

// ---- CSR build step 1: in-degree counts (int atomics, cheap) ----
__global__ void count_kernel(const int* __restrict__ dst, int* __restrict__ cnt, int E) {
    int e = blockIdx.x * blockDim.x + threadIdx.x;
    if (e < E) atomicAdd(&cnt[dst[e]], 1);
}

// ---- CSR build step 2: prefix scan (3 kernels) ----
// scan1: per-block inclusive scan of cnt -> row_ptr[i+1]; block totals -> partials
__global__ __launch_bounds__(SB)
void scan1_kernel(const int* __restrict__ cnt, int* __restrict__ row_ptr,
                  int* __restrict__ partials, int n) {
    __shared__ int s[SB];
    int i = blockIdx.x * SB + threadIdx.x;
    int v = (i < n) ? cnt[i] : 0;
    s[threadIdx.x] = v;
    __syncthreads();
    for (int off = 1; off < SB; off <<= 1) {
        int t = (threadIdx.x >= off) ? s[threadIdx.x - off] : 0;
        __syncthreads();
        s[threadIdx.x] += t;
        __syncthreads();
    }
    if (i < n) row_ptr[i + 1] = s[threadIdx.x];           // inclusive scan, shifted
    if (threadIdx.x == SB - 1) partials[blockIdx.x] = s[SB - 1];
}

// scan2: single block scans the partials (nb <= 128)
__global__ __launch_bounds__(128)
void scan2_kernel(int* __restrict__ partials, int nb) {
    __shared__ int s[128];
    int v = (threadIdx.x < nb) ? partials[threadIdx.x] : 0;
    s[threadIdx.x] = v;
    __syncthreads();
    for (int off = 1; off < 128; off <<= 1) {
        int t = (threadIdx.x >= off) ? s[threadIdx.x - off] : 0;
        __syncthreads();
        s[threadIdx.x] += t;
        __syncthreads();
    }
    if (threadIdx.x < nb) partials[threadIdx.x] = s[threadIdx.x];
}

// scan3: add block offsets; row_ptr[0] = 0
__global__ __launch_bounds__(SB)
void scan3_kernel(int* __restrict__ row_ptr, const int* __restrict__ partials, int n) {
    int i = blockIdx.x * SB + threadIdx.x;
    if (i < n && blockIdx.x > 0) row_ptr[i + 1] += partials[blockIdx.x - 1];
    if (i == 0) row_ptr[0] = 0;
}

// ---- CSR build step 3: scatter (src, weight) into slots; consumes cnt ----
__global__ void fill_kernel(const int* __restrict__ src, const int* __restrict__ dst,
                            const float* __restrict__ ew, const int* __restrict__ row_ptr,
                            int* __restrict__ cnt, int2* __restrict__ csr, int E) {
    int e = blockIdx.x * blockDim.x + threadIdx.x;
    if (e >= E) return;
    int d = dst[e];
    int pos = row_ptr[d] + atomicSub(&cnt[d], 1) - 1;
    csr[pos] = make_int2(src[e], __float_as_int(ew[e]));
}

// ---- gather-aggregate with mean folded in: one wave per node ----
// lanes 0-31 handle even edges, 32-63 odd edges; float4 per lane covers 128 ch
__global__ __launch_bounds__(256)
void gather_kernel(const float* __restrict__ feat, const int* __restrict__ row_ptr,
                   const int2* __restrict__ csr, float* __restrict__ agg, int N) {
    int node = blockIdx.x * 4 + (threadIdx.x >> 6);
    if (node >= N) return;
    int lane = threadIdx.x & 63;
    int half = lane >> 5;
    int c4 = (lane & 31) << 2;
    int r0 = row_ptr[node], r1 = row_ptr[node + 1];
    float4 acc = make_float4(0.f, 0.f, 0.f, 0.f);
    for (int r = r0 + half; r < r1; r += 2) {
        int2 e = csr[r];
        float w = __int_as_float(e.y);
        float4 v = *(const float4*)&feat[(size_t)e.x * CH + c4];
        acc.x += w * v.x; acc.y += w * v.y; acc.z += w * v.z; acc.w += w * v.w;
    }
    acc.x += __shfl_xor(acc.x, 32, 64);
    acc.y += __shfl_xor(acc.y, 32, 64);
    acc.z += __shfl_xor(acc.z, 32, 64);
    acc.w += __shfl_xor(acc.w, 32, 64);
    if (half == 0) {
        float inv = 1.0f / fmaxf((float)(r1 - r0), 1.0f);
        acc.x *= inv; acc.y *= inv; acc.z *= inv; acc.w *= inv;
        *(float4*)&agg[(size_t)node * CH + c4] = acc;
    }
}

// ---- fused layer: out = agg@w_rel + b + in@w_root  (agg pre-mean'ed) ----
template <bool RELU>
__global__ __launch_bounds__(256)
void layer_kernel(const float* __restrict__ agg,
                  const float* __restrict__ xin,
                  const float* __restrict__ w_rel,
                  const float* __restrict__ b_rel,
                  const float* __restrict__ w_root,
                  float* __restrict__ out, int N) {
    __shared__ float s_a[32][CH];
    __shared__ float s_x[32][CH];

    const int nb = blockIdx.x * 32;
    const int tid = threadIdx.x;

    for (int idx = tid; idx < 32 * 32; idx += 256) {
        int n = idx >> 5;
        int c = (idx & 31) << 2;
        int gn = nb + n;
        float4 a = make_float4(0.f, 0.f, 0.f, 0.f);
        float4 x = a;
        if (gn < N) {
            a = *(const float4*)&agg[(size_t)gn * CH + c];
            x = *(const float4*)&xin[(size_t)gn * CH + c];
        }
        *(float4*)&s_a[n][c] = a;
        *(float4*)&s_x[n][c] = x;
    }
    __syncthreads();

    const int j4 = (tid & 31) << 2;
    const int n0 = (tid >> 5) << 2;

    float4 acc[4];
#pragma unroll
    for (int nn = 0; nn < 4; nn++) acc[nn] = make_float4(0.f, 0.f, 0.f, 0.f);

    for (int k0 = 0; k0 < CH; k0 += 4) {
        float4 a[4], x[4];
#pragma unroll
        for (int nn = 0; nn < 4; nn++) {
            a[nn] = *(const float4*)&s_a[n0 + nn][k0];
            x[nn] = *(const float4*)&s_x[n0 + nn][k0];
        }
#pragma unroll
        for (int kk = 0; kk < 4; kk++) {
            float4 wr = *(const float4*)&w_rel[(size_t)(k0 + kk) * CH + j4];
            float4 wo = *(const float4*)&w_root[(size_t)(k0 + kk) * CH + j4];
#pragma unroll
            for (int nn = 0; nn < 4; nn++) {
                float av = ((const float*)&a[nn])[kk];
                float xv = ((const float*)&x[nn])[kk];
                acc[nn].x += av * wr.x + xv * wo.x;
                acc[nn].y += av * wr.y + xv * wo.y;
                acc[nn].z += av * wr.z + xv * wo.z;
                acc[nn].w += av * wr.w + xv * wo.w;
            }
        }
    }

    float4 b4 = *(const float4*)&b_rel[j4];
#pragma unroll
    for (int nn = 0; nn < 4; nn++) {
        int gn = nb + n0 + nn;
        if (gn >= N) continue;
        float4 r;
        r.x = acc[nn].x + b4.x;
        r.y = acc[nn].y + b4.y;
        r.z = acc[nn].z + b4.z;
        r.w = acc[nn].w + b4.w;
        if (RELU) {
            r.x = fmaxf(r.x, 0.f); r.y = fmaxf(r.y, 0.f);
            r.z = fmaxf(r.z, 0.f); r.w = fmaxf(r.w, 0.f);
        }
        *(float4*)&out[(size_t)gn * CH + j4] = r;
    }
}

// ---- decode: one wave per pair ----
__global__ void decode_kernel(const float* __restrict__ z,
                              const int* __restrict__ ps,
                              const int* __restrict__ pd,
                              float* __restrict__ out, int P) {
    long tid = (long)blockIdx.x * blockDim.x + threadIdx.x;
    int p = (int)(tid >> 6);
    int lane = (int)(tid & 63);
    if (p >= P) return;
    int s = ps[p], d = pd[p];
    float2 a = *(const float2*)&z[(size_t)s * CH + lane * 2];
    float2 b = *(const float2*)&z[(size_t)d * CH + lane * 2];
    float v = a.x * b.x + a.y * b.y;
#pragma unroll
    for (int off = 32; off > 0; off >>= 1) v += __shfl_down(v, off, 64);
    if (lane == 0) out[p] = v * 0.08838834764831845f;  // 1/sqrt(128)
}

extern "C" void kernel_launch(void* const* d_in, const int* in_sizes, int n_in,
                              void* d_out, int out_size, void* d_ws, size_t ws_size,
                              hipStream_t stream) {
    const float* x       = (const float*)d_in[0];
    const int*   ei      = (const int*)d_in[1];   // [2, E]: src then dst
    const float* ew      = (const float*)d_in[2];
    const int*   eli     = (const int*)d_in[3];   // [2, P]
    const float* w1_rel  = (const float*)d_in[4];
    const float* b1      = (const float*)d_in[5];
    const float* w1_root = (const float*)d_in[6];
    const float* w2_rel  = (const float*)d_in[7];
    const float* b2      = (const float*)d_in[8];
    const float* w2_root = (const float*)d_in[9];
    float* out = (float*)d_out;

    const int N = NN, E = NE, P = NP;
    const size_t rowbytes = (size_t)N * CH * sizeof(float);

    char* ws = (char*)d_ws;
    float* agg = (float*)(ws);
    float* h   = (float*)(ws + rowbytes);
    float* z   = agg;                       // alias: layer2 reads/writes same rows per block
    size_t off = 2 * rowbytes;
    int* cnt      = (int*)(ws + off); off += (size_t)N * 4;
    int* row_ptr  = (int*)(ws + off); off += (size_t)(N + 1) * 4;
    int* partials = (int*)(ws + off); off += 256 * 4;
    off = (off + 15) & ~(size_t)15;
    int2* csr     = (int2*)(ws + off);      // E * 8 bytes

    const int* src = ei;
    const int* dst = ei + E;

    const int nb_scan = (N + SB - 1) / SB;  // 98

    // --- CSR build ---
    hipMemsetAsync(cnt, 0, (size_t)N * 4, stream);
    count_kernel<<<(E + 255) / 256, 256, 0, stream>>>(dst, cnt, E);
    scan1_kernel<<<nb_scan, SB, 0, stream>>>(cnt, row_ptr, partials, N);
    scan2_kernel<<<1, 128, 0, stream>>>(partials, nb_scan);
    scan3_kernel<<<nb_scan, SB, 0, stream>>>(row_ptr, partials, N);
    fill_kernel<<<(E + 255) / 256, 256, 0, stream>>>(src, dst, ew, row_ptr, cnt, csr, E);

    // --- layer 1 ---
    gather_kernel<<<(N + 3) / 4, 256, 0, stream>>>(x, row_ptr, csr, agg, N);
    layer_kernel<true><<<(N + 31) / 32, 256, 0, stream>>>(agg, x, w1_rel, b1, w1_root, h, N);

    // --- layer 2 ---
    gather_kernel<<<(N + 3) / 4, 256, 0, stream>>>(h, row_ptr, csr, agg, N);
    layer_kernel<false><<<(N + 31) / 32, 256, 0, stream>>>(agg, h, w2_rel, b2, w2_root, z, N);

    // --- decode ---
    {
        long threads = (long)P * 64;
        decode_kernel<<<(int)((threads + 255) / 256), 256, 0, stream>>>(z, eli, eli + P, out, P);
    }
}

// Round 3
// 618.112 us; speedup vs baseline: 9.4205x; 1.4614x over previous
//
#include <hip/hip_runtime.h>

#define NN 100000
#define NE 1600000
#define NP 200000
#define CH 128
#define SB 1024   // scan block size
#define LK 264    // padded LDS row stride (in fp16 elems): 2-way-max bank pattern

typedef _Float16 f16x8 __attribute__((ext_vector_type(8)));
typedef _Float16 f16x4 __attribute__((ext_vector_type(4)));
typedef float f32x4 __attribute__((ext_vector_type(4)));

// ---- CSR build step 1: in-degree counts ----
__global__ void count_kernel(const int* __restrict__ dst, int* __restrict__ cnt, int E) {
    int e = blockIdx.x * blockDim.x + threadIdx.x;
    if (e < E) atomicAdd(&cnt[dst[e]], 1);
}

// ---- CSR build step 2: prefix scan (3 kernels) ----
__global__ __launch_bounds__(SB)
void scan1_kernel(const int* __restrict__ cnt, int* __restrict__ row_ptr,
                  int* __restrict__ partials, int n) {
    __shared__ int s[SB];
    int i = blockIdx.x * SB + threadIdx.x;
    int v = (i < n) ? cnt[i] : 0;
    s[threadIdx.x] = v;
    __syncthreads();
    for (int off = 1; off < SB; off <<= 1) {
        int t = (threadIdx.x >= off) ? s[threadIdx.x - off] : 0;
        __syncthreads();
        s[threadIdx.x] += t;
        __syncthreads();
    }
    if (i < n) row_ptr[i + 1] = s[threadIdx.x];
    if (threadIdx.x == SB - 1) partials[blockIdx.x] = s[SB - 1];
}

__global__ __launch_bounds__(128)
void scan2_kernel(int* __restrict__ partials, int nb) {
    __shared__ int s[128];
    int v = (threadIdx.x < nb) ? partials[threadIdx.x] : 0;
    s[threadIdx.x] = v;
    __syncthreads();
    for (int off = 1; off < 128; off <<= 1) {
        int t = (threadIdx.x >= off) ? s[threadIdx.x - off] : 0;
        __syncthreads();
        s[threadIdx.x] += t;
        __syncthreads();
    }
    if (threadIdx.x < nb) partials[threadIdx.x] = s[threadIdx.x];
}

__global__ __launch_bounds__(SB)
void scan3_kernel(int* __restrict__ row_ptr, const int* __restrict__ partials, int n) {
    int i = blockIdx.x * SB + threadIdx.x;
    if (i < n && blockIdx.x > 0) row_ptr[i + 1] += partials[blockIdx.x - 1];
    if (i == 0) row_ptr[0] = 0;
}

// ---- CSR build step 3: fill slots ----
__global__ void fill_kernel(const int* __restrict__ src, const int* __restrict__ dst,
                            const float* __restrict__ ew, const int* __restrict__ row_ptr,
                            int* __restrict__ cnt, int2* __restrict__ csr, int E) {
    int e = blockIdx.x * blockDim.x + threadIdx.x;
    if (e >= E) return;
    int d = dst[e];
    int pos = row_ptr[d] + atomicSub(&cnt[d], 1) - 1;
    csr[pos] = make_int2(src[e], __float_as_int(ew[e]));
}

// ---- gather-aggregate (mean folded): one wave per node ----
__global__ __launch_bounds__(256)
void gather_kernel(const float* __restrict__ feat, const int* __restrict__ row_ptr,
                   const int2* __restrict__ csr, float* __restrict__ agg, int N) {
    int node = blockIdx.x * 4 + (threadIdx.x >> 6);
    if (node >= N) return;
    int lane = threadIdx.x & 63;
    int half = lane >> 5;
    int c4 = (lane & 31) << 2;
    int r0 = row_ptr[node], r1 = row_ptr[node + 1];
    float4 acc = make_float4(0.f, 0.f, 0.f, 0.f);
    for (int r = r0 + half; r < r1; r += 2) {
        int2 e = csr[r];
        float w = __int_as_float(e.y);
        float4 v = *(const float4*)&feat[(size_t)e.x * CH + c4];
        acc.x += w * v.x; acc.y += w * v.y; acc.z += w * v.z; acc.w += w * v.w;
    }
    acc.x += __shfl_xor(acc.x, 32, 64);
    acc.y += __shfl_xor(acc.y, 32, 64);
    acc.z += __shfl_xor(acc.z, 32, 64);
    acc.w += __shfl_xor(acc.w, 32, 64);
    if (half == 0) {
        float inv = 1.0f / fmaxf((float)(r1 - r0), 1.0f);
        acc.x *= inv; acc.y *= inv; acc.z *= inv; acc.w *= inv;
        *(float4*)&agg[(size_t)node * CH + c4] = acc;
    }
}

// ---- weight prep: Wt[n][k] fp16, n in [0,128), k in [0,256): k<128 -> w_rel, else w_root ----
__global__ void prep_w_kernel(const float* __restrict__ wr, const float* __restrict__ wo,
                              _Float16* __restrict__ wt) {
    int idx = blockIdx.x * 256 + threadIdx.x;
    if (idx >= 128 * 256) return;
    int n = idx >> 8, k = idx & 255;
    float v = (k < 128) ? wr[k * 128 + n] : wo[(k - 128) * 128 + n];
    wt[idx] = (_Float16)v;
}

// ---- MFMA layer: out[n x 128] = [agg | xin] @ Wt^T + b  (optional relu) ----
// block = 256 threads (4 waves); tile = 64 nodes x 128 outs; K = 256 in 8 steps of 32
template <bool RELU>
__global__ __launch_bounds__(256)
void layer_mfma_kernel(const float* __restrict__ agg,
                       const float* __restrict__ xin,
                       const _Float16* __restrict__ wt,
                       const float* __restrict__ bias,
                       float* __restrict__ out, int N) {
    __shared__ _Float16 s_a[64][LK];   // 33792 B

    const int tid = threadIdx.x;
    const int nb = blockIdx.x * 64;

    // stage A tile: 64 rows x 256 k (fp32 -> fp16)
    for (int i = tid; i < 64 * 64; i += 256) {
        int r = i >> 6;
        int c4 = (i & 63) << 2;   // k index
        int gn = nb + r;
        float4 v = make_float4(0.f, 0.f, 0.f, 0.f);
        if (gn < N) {
            const float* srcp = (c4 < 128) ? &agg[(size_t)gn * CH + c4]
                                           : &xin[(size_t)gn * CH + (c4 - 128)];
            v = *(const float4*)srcp;
        }
        f16x4 hv = { (_Float16)v.x, (_Float16)v.y, (_Float16)v.z, (_Float16)v.w };
        *(f16x4*)&s_a[r][c4] = hv;
    }
    __syncthreads();

    const int wave = tid >> 6;
    const int lane = tid & 63;
    const int quad = lane >> 4;
    const int l16  = lane & 15;

    f32x4 acc[4][2];
#pragma unroll
    for (int m = 0; m < 4; m++)
#pragma unroll
        for (int t = 0; t < 2; t++) acc[m][t] = (f32x4){0.f, 0.f, 0.f, 0.f};

    const int kq = quad * 8;   // k offset within 32-wide step

#pragma unroll
    for (int ks = 0; ks < 8; ks++) {
        int kbase = ks * 32 + kq;
        f16x8 bf[2];
#pragma unroll
        for (int t = 0; t < 2; t++) {
            int n = wave * 32 + t * 16 + l16;
            bf[t] = *(const f16x8*)&wt[(size_t)n * 256 + kbase];
        }
#pragma unroll
        for (int m = 0; m < 4; m++) {
            f16x8 af = *(const f16x8*)&s_a[m * 16 + l16][kbase];
            acc[m][0] = __builtin_amdgcn_mfma_f32_16x16x32_f16(af, bf[0], acc[m][0], 0, 0, 0);
            acc[m][1] = __builtin_amdgcn_mfma_f32_16x16x32_f16(af, bf[1], acc[m][1], 0, 0, 0);
        }
    }

    float bv[2];
    bv[0] = bias[wave * 32 + l16];
    bv[1] = bias[wave * 32 + 16 + l16];

#pragma unroll
    for (int m = 0; m < 4; m++) {
#pragma unroll
        for (int r = 0; r < 4; r++) {
            int node = nb + m * 16 + quad * 4 + r;
            if (node >= N) continue;
#pragma unroll
            for (int t = 0; t < 2; t++) {
                float v = acc[m][t][r] + bv[t];
                if (RELU) v = fmaxf(v, 0.f);
                out[(size_t)node * CH + wave * 32 + t * 16 + l16] = v;
            }
        }
    }
}

// ---- decode: one wave per pair ----
__global__ void decode_kernel(const float* __restrict__ z,
                              const int* __restrict__ ps,
                              const int* __restrict__ pd,
                              float* __restrict__ out, int P) {
    long tid = (long)blockIdx.x * blockDim.x + threadIdx.x;
    int p = (int)(tid >> 6);
    int lane = (int)(tid & 63);
    if (p >= P) return;
    int s = ps[p], d = pd[p];
    float2 a = *(const float2*)&z[(size_t)s * CH + lane * 2];
    float2 b = *(const float2*)&z[(size_t)d * CH + lane * 2];
    float v = a.x * b.x + a.y * b.y;
#pragma unroll
    for (int off = 32; off > 0; off >>= 1) v += __shfl_down(v, off, 64);
    if (lane == 0) out[p] = v * 0.08838834764831845f;  // 1/sqrt(128)
}

extern "C" void kernel_launch(void* const* d_in, const int* in_sizes, int n_in,
                              void* d_out, int out_size, void* d_ws, size_t ws_size,
                              hipStream_t stream) {
    const float* x       = (const float*)d_in[0];
    const int*   ei      = (const int*)d_in[1];   // [2, E]: src then dst
    const float* ew      = (const float*)d_in[2];
    const int*   eli     = (const int*)d_in[3];   // [2, P]
    const float* w1_rel  = (const float*)d_in[4];
    const float* b1      = (const float*)d_in[5];
    const float* w1_root = (const float*)d_in[6];
    const float* w2_rel  = (const float*)d_in[7];
    const float* b2      = (const float*)d_in[8];
    const float* w2_root = (const float*)d_in[9];
    float* out = (float*)d_out;

    const int N = NN, E = NE, P = NP;
    const size_t rowbytes = (size_t)N * CH * sizeof(float);

    char* ws = (char*)d_ws;
    float* agg = (float*)(ws);
    float* h   = (float*)(ws + rowbytes);
    float* z   = agg;                       // alias: safe, block-private rows
    size_t off = 2 * rowbytes;
    int* cnt      = (int*)(ws + off); off += (size_t)N * 4;
    int* row_ptr  = (int*)(ws + off); off += (size_t)(N + 1) * 4;
    int* partials = (int*)(ws + off); off += 256 * 4;
    off = (off + 15) & ~(size_t)15;
    int2* csr     = (int2*)(ws + off); off += (size_t)E * 8;
    _Float16* w1t = (_Float16*)(ws + off); off += (size_t)128 * 256 * 2;
    _Float16* w2t = (_Float16*)(ws + off); off += (size_t)128 * 256 * 2;

    const int* src = ei;
    const int* dst = ei + E;

    const int nb_scan = (N + SB - 1) / SB;  // 98

    // --- weight prep (fp32 -> fp16 transposed) ---
    prep_w_kernel<<<128, 256, 0, stream>>>(w1_rel, w1_root, w1t);
    prep_w_kernel<<<128, 256, 0, stream>>>(w2_rel, w2_root, w2t);

    // --- CSR build ---
    hipMemsetAsync(cnt, 0, (size_t)N * 4, stream);
    count_kernel<<<(E + 255) / 256, 256, 0, stream>>>(dst, cnt, E);
    scan1_kernel<<<nb_scan, SB, 0, stream>>>(cnt, row_ptr, partials, N);
    scan2_kernel<<<1, 128, 0, stream>>>(partials, nb_scan);
    scan3_kernel<<<nb_scan, SB, 0, stream>>>(row_ptr, partials, N);
    fill_kernel<<<(E + 255) / 256, 256, 0, stream>>>(src, dst, ew, row_ptr, cnt, csr, E);

    // --- layer 1 ---
    gather_kernel<<<(N + 3) / 4, 256, 0, stream>>>(x, row_ptr, csr, agg, N);
    layer_mfma_kernel<true><<<(N + 63) / 64, 256, 0, stream>>>(agg, x, w1t, b1, h, N);

    // --- layer 2 ---
    gather_kernel<<<(N + 3) / 4, 256, 0, stream>>>(h, row_ptr, csr, agg, N);
    layer_mfma_kernel<false><<<(N + 63) / 64, 256, 0, stream>>>(agg, h, w2t, b2, z, N);

    // --- decode ---
    {
        long threads = (long)P * 64;
        decode_kernel<<<(int)((threads + 255) / 256), 256, 0, stream>>>(z, eli, eli + P, out, P);
    }
}

// Round 4
// 448.444 us; speedup vs baseline: 12.9847x; 1.3783x over previous
//
#include <hip/hip_runtime.h>

#define NN 100000
#define NE 1600000
#define NP 200000
#define CH 128
#define SB 1024   // scan block size
#define LK 264    // padded LDS row stride (fp16 elems)

typedef _Float16 f16x8 __attribute__((ext_vector_type(8)));
typedef _Float16 f16x4 __attribute__((ext_vector_type(4)));
typedef _Float16 f16x2 __attribute__((ext_vector_type(2)));
typedef float f32x4 __attribute__((ext_vector_type(4)));

// ---- fp32 -> fp16 row cast: one thread per 8 elems ----
__global__ void cast_kernel(const float* __restrict__ in, _Float16* __restrict__ out, int n8) {
    int i = blockIdx.x * blockDim.x + threadIdx.x;
    if (i >= n8) return;
    const float4* p = (const float4*)in + (size_t)i * 2;
    float4 a = p[0], b = p[1];
    f16x8 o = { (_Float16)a.x, (_Float16)a.y, (_Float16)a.z, (_Float16)a.w,
                (_Float16)b.x, (_Float16)b.y, (_Float16)b.z, (_Float16)b.w };
    *((f16x8*)out + i) = o;
}

// ---- CSR step 1: count + save per-edge rank (kills the second atomic pass) ----
__global__ void count_rank_kernel(const int* __restrict__ dst, int* __restrict__ cnt,
                                  int* __restrict__ rank, int E) {
    int e = blockIdx.x * blockDim.x + threadIdx.x;
    if (e < E) rank[e] = atomicAdd(&cnt[dst[e]], 1);
}

// ---- CSR step 2: prefix scan (3 kernels) ----
__global__ __launch_bounds__(SB)
void scan1_kernel(const int* __restrict__ cnt, int* __restrict__ row_ptr,
                  int* __restrict__ partials, int n) {
    __shared__ int s[SB];
    int i = blockIdx.x * SB + threadIdx.x;
    int v = (i < n) ? cnt[i] : 0;
    s[threadIdx.x] = v;
    __syncthreads();
    for (int off = 1; off < SB; off <<= 1) {
        int t = (threadIdx.x >= off) ? s[threadIdx.x - off] : 0;
        __syncthreads();
        s[threadIdx.x] += t;
        __syncthreads();
    }
    if (i < n) row_ptr[i + 1] = s[threadIdx.x];
    if (threadIdx.x == SB - 1) partials[blockIdx.x] = s[SB - 1];
}

__global__ __launch_bounds__(128)
void scan2_kernel(int* __restrict__ partials, int nb) {
    __shared__ int s[128];
    int v = (threadIdx.x < nb) ? partials[threadIdx.x] : 0;
    s[threadIdx.x] = v;
    __syncthreads();
    for (int off = 1; off < 128; off <<= 1) {
        int t = (threadIdx.x >= off) ? s[threadIdx.x - off] : 0;
        __syncthreads();
        s[threadIdx.x] += t;
        __syncthreads();
    }
    if (threadIdx.x < nb) partials[threadIdx.x] = s[threadIdx.x];
}

__global__ __launch_bounds__(SB)
void scan3_kernel(int* __restrict__ row_ptr, const int* __restrict__ partials, int n) {
    int i = blockIdx.x * SB + threadIdx.x;
    if (i < n && blockIdx.x > 0) row_ptr[i + 1] += partials[blockIdx.x - 1];
    if (i == 0) row_ptr[0] = 0;
}

// ---- CSR step 3: fill via precomputed ranks (no atomics) ----
__global__ void fill_kernel(const int* __restrict__ src, const int* __restrict__ dst,
                            const float* __restrict__ ew, const int* __restrict__ row_ptr,
                            const int* __restrict__ rank, int2* __restrict__ csr, int E) {
    int e = blockIdx.x * blockDim.x + threadIdx.x;
    if (e >= E) return;
    int pos = row_ptr[dst[e]] + rank[e];
    csr[pos] = make_int2(src[e], __float_as_int(ew[e]));
}

// ---- gather-aggregate (mean folded): one wave per node, 4 edges in flight ----
// quarter q (16 lanes x f16x8 = 256 B) covers one full feature row
__global__ __launch_bounds__(256)
void gather_kernel(const _Float16* __restrict__ feat, const int* __restrict__ row_ptr,
                   const int2* __restrict__ csr, _Float16* __restrict__ agg, int N) {
    int node = blockIdx.x * 4 + (threadIdx.x >> 6);
    if (node >= N) return;
    int lane = threadIdx.x & 63;
    int q = lane >> 4;
    int l16 = lane & 15;
    int c8 = l16 << 3;
    int r0 = row_ptr[node], r1 = row_ptr[node + 1];
    float acc[8] = {0.f, 0.f, 0.f, 0.f, 0.f, 0.f, 0.f, 0.f};
    for (int r = r0 + q; r < r1; r += 4) {
        int2 e = csr[r];
        float w = __int_as_float(e.y);
        f16x8 v = *(const f16x8*)&feat[(size_t)e.x * CH + c8];
#pragma unroll
        for (int j = 0; j < 8; j++) acc[j] += w * (float)v[j];
    }
#pragma unroll
    for (int j = 0; j < 8; j++) {
        acc[j] += __shfl_xor(acc[j], 16, 64);
        acc[j] += __shfl_xor(acc[j], 32, 64);
    }
    if (q == 0) {
        float inv = 1.0f / fmaxf((float)(r1 - r0), 1.0f);
        f16x8 o;
#pragma unroll
        for (int j = 0; j < 8; j++) o[j] = (_Float16)(acc[j] * inv);
        *(f16x8*)&agg[(size_t)node * CH + c8] = o;
    }
}

// ---- weight prep: Wt[n][k] fp16, k<128 -> w_rel, else w_root ----
__global__ void prep_w_kernel(const float* __restrict__ wr, const float* __restrict__ wo,
                              _Float16* __restrict__ wt) {
    int idx = blockIdx.x * 256 + threadIdx.x;
    if (idx >= 128 * 256) return;
    int n = idx >> 8, k = idx & 255;
    float v = (k < 128) ? wr[k * 128 + n] : wo[(k - 128) * 128 + n];
    wt[idx] = (_Float16)v;
}

// ---- MFMA layer: out[n x 128] = [agg | xin] @ Wt^T + b  (optional relu), fp16 in/out ----
template <bool RELU>
__global__ __launch_bounds__(256)
void layer_mfma_kernel(const _Float16* __restrict__ agg,
                       const _Float16* __restrict__ xin,
                       const _Float16* __restrict__ wt,
                       const float* __restrict__ bias,
                       _Float16* __restrict__ out, int N) {
    __shared__ _Float16 s_a[64][LK];   // 33792 B

    const int tid = threadIdx.x;
    const int nb = blockIdx.x * 64;

    // stage A tile: 64 rows x 256 k, fp16 direct (8 iters of f16x8)
    for (int i = tid; i < 64 * 32; i += 256) {
        int r = i >> 5;
        int c8 = (i & 31) << 3;   // k index
        int gn = nb + r;
        f16x8 v = {};
        if (gn < N) {
            const _Float16* srcp = (c8 < 128) ? &agg[(size_t)gn * CH + c8]
                                              : &xin[(size_t)gn * CH + (c8 - 128)];
            v = *(const f16x8*)srcp;
        }
        *(f16x8*)&s_a[r][c8] = v;
    }
    __syncthreads();

    const int wave = tid >> 6;
    const int lane = tid & 63;
    const int quad = lane >> 4;
    const int l16  = lane & 15;

    f32x4 acc[4][2];
#pragma unroll
    for (int m = 0; m < 4; m++)
#pragma unroll
        for (int t = 0; t < 2; t++) acc[m][t] = (f32x4){0.f, 0.f, 0.f, 0.f};

    const int kq = quad * 8;

#pragma unroll
    for (int ks = 0; ks < 8; ks++) {
        int kbase = ks * 32 + kq;
        f16x8 bf[2];
#pragma unroll
        for (int t = 0; t < 2; t++) {
            int n = wave * 32 + t * 16 + l16;
            bf[t] = *(const f16x8*)&wt[(size_t)n * 256 + kbase];
        }
#pragma unroll
        for (int m = 0; m < 4; m++) {
            f16x8 af = *(const f16x8*)&s_a[m * 16 + l16][kbase];
            acc[m][0] = __builtin_amdgcn_mfma_f32_16x16x32_f16(af, bf[0], acc[m][0], 0, 0, 0);
            acc[m][1] = __builtin_amdgcn_mfma_f32_16x16x32_f16(af, bf[1], acc[m][1], 0, 0, 0);
        }
    }

    float bv[2];
    bv[0] = bias[wave * 32 + l16];
    bv[1] = bias[wave * 32 + 16 + l16];

#pragma unroll
    for (int m = 0; m < 4; m++) {
#pragma unroll
        for (int r = 0; r < 4; r++) {
            int node = nb + m * 16 + quad * 4 + r;
            if (node >= N) continue;
#pragma unroll
            for (int t = 0; t < 2; t++) {
                float v = acc[m][t][r] + bv[t];
                if (RELU) v = fmaxf(v, 0.f);
                out[(size_t)node * CH + wave * 32 + t * 16 + l16] = (_Float16)v;
            }
        }
    }
}

// ---- decode: one wave per pair, fp16 z ----
__global__ void decode_kernel(const _Float16* __restrict__ z,
                              const int* __restrict__ ps,
                              const int* __restrict__ pd,
                              float* __restrict__ out, int P) {
    long tid = (long)blockIdx.x * blockDim.x + threadIdx.x;
    int p = (int)(tid >> 6);
    int lane = (int)(tid & 63);
    if (p >= P) return;
    int s = ps[p], d = pd[p];
    f16x2 a = *(const f16x2*)&z[(size_t)s * CH + lane * 2];
    f16x2 b = *(const f16x2*)&z[(size_t)d * CH + lane * 2];
    float v = (float)a[0] * (float)b[0] + (float)a[1] * (float)b[1];
#pragma unroll
    for (int off = 32; off > 0; off >>= 1) v += __shfl_down(v, off, 64);
    if (lane == 0) out[p] = v * 0.08838834764831845f;  // 1/sqrt(128)
}

extern "C" void kernel_launch(void* const* d_in, const int* in_sizes, int n_in,
                              void* d_out, int out_size, void* d_ws, size_t ws_size,
                              hipStream_t stream) {
    const float* x       = (const float*)d_in[0];
    const int*   ei      = (const int*)d_in[1];   // [2, E]: src then dst
    const float* ew      = (const float*)d_in[2];
    const int*   eli     = (const int*)d_in[3];   // [2, P]
    const float* w1_rel  = (const float*)d_in[4];
    const float* b1      = (const float*)d_in[5];
    const float* w1_root = (const float*)d_in[6];
    const float* w2_rel  = (const float*)d_in[7];
    const float* b2      = (const float*)d_in[8];
    const float* w2_root = (const float*)d_in[9];
    float* out = (float*)d_out;

    const int N = NN, E = NE, P = NP;
    const size_t hrow = (size_t)N * CH * sizeof(_Float16);   // 25.6 MB

    char* ws = (char*)d_ws;
    _Float16* xh   = (_Float16*)(ws);
    _Float16* aggh = (_Float16*)(ws + hrow);
    _Float16* hh   = (_Float16*)(ws + 2 * hrow);
    _Float16* zh   = aggh;                  // alias: block reads its rows before writing
    size_t off = 3 * hrow;
    int* cnt      = (int*)(ws + off); off += (size_t)N * 4;
    int* row_ptr  = (int*)(ws + off); off += (size_t)(N + 1) * 4;
    int* partials = (int*)(ws + off); off += 256 * 4;
    int* rank     = (int*)(ws + off); off += (size_t)E * 4;
    off = (off + 15) & ~(size_t)15;
    int2* csr     = (int2*)(ws + off); off += (size_t)E * 8;
    _Float16* w1t = (_Float16*)(ws + off); off += (size_t)128 * 256 * 2;
    _Float16* w2t = (_Float16*)(ws + off); off += (size_t)128 * 256 * 2;

    const int* src = ei;
    const int* dst = ei + E;

    const int nb_scan = (N + SB - 1) / SB;  // 98
    const int n8 = N * CH / 8;              // 1.6M

    // --- prep: cast x, transpose weights ---
    cast_kernel<<<(n8 + 255) / 256, 256, 0, stream>>>(x, xh, n8);
    prep_w_kernel<<<128, 256, 0, stream>>>(w1_rel, w1_root, w1t);
    prep_w_kernel<<<128, 256, 0, stream>>>(w2_rel, w2_root, w2t);

    // --- CSR build ---
    hipMemsetAsync(cnt, 0, (size_t)N * 4, stream);
    count_rank_kernel<<<(E + 255) / 256, 256, 0, stream>>>(dst, cnt, rank, E);
    scan1_kernel<<<nb_scan, SB, 0, stream>>>(cnt, row_ptr, partials, N);
    scan2_kernel<<<1, 128, 0, stream>>>(partials, nb_scan);
    scan3_kernel<<<nb_scan, SB, 0, stream>>>(row_ptr, partials, N);
    fill_kernel<<<(E + 255) / 256, 256, 0, stream>>>(src, dst, ew, row_ptr, rank, csr, E);

    // --- layer 1 ---
    gather_kernel<<<(N + 3) / 4, 256, 0, stream>>>(xh, row_ptr, csr, aggh, N);
    layer_mfma_kernel<true><<<(N + 63) / 64, 256, 0, stream>>>(aggh, xh, w1t, b1, hh, N);

    // --- layer 2 ---
    gather_kernel<<<(N + 3) / 4, 256, 0, stream>>>(hh, row_ptr, csr, aggh, N);
    layer_mfma_kernel<false><<<(N + 63) / 64, 256, 0, stream>>>(aggh, hh, w2t, b2, zh, N);

    // --- decode ---
    {
        long threads = (long)P * 64;
        decode_kernel<<<(int)((threads + 255) / 256), 256, 0, stream>>>(zh, eli, eli + P, out, P);
    }
}

// Round 5
// 439.817 us; speedup vs baseline: 13.2393x; 1.0196x over previous
//
#include <hip/hip_runtime.h>

#define NN 100000
#define NE 1600000
#define NP 200000
#define CH 128
#define SB 1024   // scan block size
#define LK 264    // padded LDS row stride (fp16 elems)
#define CPAD 16   // cnt padding: one counter per 64B line

typedef _Float16 f16x8 __attribute__((ext_vector_type(8)));
typedef _Float16 f16x2 __attribute__((ext_vector_type(2)));
typedef float f32x4 __attribute__((ext_vector_type(4)));

// ---- fp32 -> fp16 row cast ----
__global__ void cast_kernel(const float* __restrict__ in, _Float16* __restrict__ out, int n8) {
    int i = blockIdx.x * blockDim.x + threadIdx.x;
    if (i >= n8) return;
    const float4* p = (const float4*)in + (size_t)i * 2;
    float4 a = p[0], b = p[1];
    f16x8 o = { (_Float16)a.x, (_Float16)a.y, (_Float16)a.z, (_Float16)a.w,
                (_Float16)b.x, (_Float16)b.y, (_Float16)b.z, (_Float16)b.w };
    *((f16x8*)out + i) = o;
}

// ---- CSR step 1: count + rank, 8 edges per thread (ILP on returning atomics) ----
// cnt is padded: counter for node d lives at cnt[d * CPAD]
__global__ void count_rank_kernel(const int* __restrict__ dst, int* __restrict__ cnt,
                                  int* __restrict__ rank, int E) {
    int t = blockIdx.x * blockDim.x + threadIdx.x;
    int e0 = t * 8;
    if (e0 >= E) return;
    int4 d0 = *(const int4*)&dst[e0];
    int4 d1 = *(const int4*)&dst[e0 + 4];
    int4 r0, r1;
    r0.x = atomicAdd(&cnt[d0.x * CPAD], 1);
    r0.y = atomicAdd(&cnt[d0.y * CPAD], 1);
    r0.z = atomicAdd(&cnt[d0.z * CPAD], 1);
    r0.w = atomicAdd(&cnt[d0.w * CPAD], 1);
    r1.x = atomicAdd(&cnt[d1.x * CPAD], 1);
    r1.y = atomicAdd(&cnt[d1.y * CPAD], 1);
    r1.z = atomicAdd(&cnt[d1.z * CPAD], 1);
    r1.w = atomicAdd(&cnt[d1.w * CPAD], 1);
    *(int4*)&rank[e0] = r0;
    *(int4*)&rank[e0 + 4] = r1;
}

// ---- CSR step 2: prefix scan (3 kernels); reads padded cnt ----
__global__ __launch_bounds__(SB)
void scan1_kernel(const int* __restrict__ cnt, int* __restrict__ row_ptr,
                  int* __restrict__ partials, int n) {
    __shared__ int s[SB];
    int i = blockIdx.x * SB + threadIdx.x;
    int v = (i < n) ? cnt[i * CPAD] : 0;
    s[threadIdx.x] = v;
    __syncthreads();
    for (int off = 1; off < SB; off <<= 1) {
        int t = (threadIdx.x >= off) ? s[threadIdx.x - off] : 0;
        __syncthreads();
        s[threadIdx.x] += t;
        __syncthreads();
    }
    if (i < n) row_ptr[i + 1] = s[threadIdx.x];
    if (threadIdx.x == SB - 1) partials[blockIdx.x] = s[SB - 1];
}

__global__ __launch_bounds__(128)
void scan2_kernel(int* __restrict__ partials, int nb) {
    __shared__ int s[128];
    int v = (threadIdx.x < nb) ? partials[threadIdx.x] : 0;
    s[threadIdx.x] = v;
    __syncthreads();
    for (int off = 1; off < 128; off <<= 1) {
        int t = (threadIdx.x >= off) ? s[threadIdx.x - off] : 0;
        __syncthreads();
        s[threadIdx.x] += t;
        __syncthreads();
    }
    if (threadIdx.x < nb) partials[threadIdx.x] = s[threadIdx.x];
}

__global__ __launch_bounds__(SB)
void scan3_kernel(int* __restrict__ row_ptr, const int* __restrict__ partials, int n) {
    int i = blockIdx.x * SB + threadIdx.x;
    if (i < n && blockIdx.x > 0) row_ptr[i + 1] += partials[blockIdx.x - 1];
    if (i == 0) row_ptr[0] = 0;
}

// ---- CSR step 3: fill via precomputed ranks (no atomics) ----
__global__ void fill_kernel(const int* __restrict__ src, const int* __restrict__ dst,
                            const float* __restrict__ ew, const int* __restrict__ row_ptr,
                            const int* __restrict__ rank, int2* __restrict__ csr, int E) {
    int e = blockIdx.x * blockDim.x + threadIdx.x;
    if (e >= E) return;
    int pos = row_ptr[dst[e]] + rank[e];
    csr[pos] = make_int2(src[e], __float_as_int(ew[e]));
}

// ---- gather-aggregate (mean folded): one wave per node, 4 edges in flight,
//      2-deep software pipeline per quarter ----
__global__ __launch_bounds__(256)
void gather_kernel(const _Float16* __restrict__ feat, const int* __restrict__ row_ptr,
                   const int2* __restrict__ csr, _Float16* __restrict__ agg, int N) {
    int node = blockIdx.x * 4 + (threadIdx.x >> 6);
    if (node >= N) return;
    int lane = threadIdx.x & 63;
    int q = lane >> 4;
    int l16 = lane & 15;
    int c8 = l16 << 3;
    int r0 = row_ptr[node], r1 = row_ptr[node + 1];
    float acc[8] = {0.f, 0.f, 0.f, 0.f, 0.f, 0.f, 0.f, 0.f};
    int r = r0 + q;
    if (r < r1) {
        int2 e = csr[r];
        f16x8 v = *(const f16x8*)&feat[(size_t)e.x * CH + c8];
        for (r += 4; r < r1; r += 4) {
            int2 e2 = csr[r];
            f16x8 v2 = *(const f16x8*)&feat[(size_t)e2.x * CH + c8];
            float w = __int_as_float(e.y);
#pragma unroll
            for (int j = 0; j < 8; j++) acc[j] += w * (float)v[j];
            e = e2; v = v2;
        }
        float w = __int_as_float(e.y);
#pragma unroll
        for (int j = 0; j < 8; j++) acc[j] += w * (float)v[j];
    }
#pragma unroll
    for (int j = 0; j < 8; j++) {
        acc[j] += __shfl_xor(acc[j], 16, 64);
        acc[j] += __shfl_xor(acc[j], 32, 64);
    }
    if (q == 0) {
        float inv = 1.0f / fmaxf((float)(r1 - r0), 1.0f);
        f16x8 o;
#pragma unroll
        for (int j = 0; j < 8; j++) o[j] = (_Float16)(acc[j] * inv);
        *(f16x8*)&agg[(size_t)node * CH + c8] = o;
    }
}

// ---- weight prep: Wt[n][k] fp16, k<128 -> w_rel, else w_root ----
__global__ void prep_w_kernel(const float* __restrict__ wr, const float* __restrict__ wo,
                              _Float16* __restrict__ wt) {
    int idx = blockIdx.x * 256 + threadIdx.x;
    if (idx >= 128 * 256) return;
    int n = idx >> 8, k = idx & 255;
    float v = (k < 128) ? wr[k * 128 + n] : wo[(k - 128) * 128 + n];
    wt[idx] = (_Float16)v;
}

// ---- MFMA layer: out[n x 128] = [agg | xin] @ Wt^T + b  (optional relu), fp16 in/out ----
template <bool RELU>
__global__ __launch_bounds__(256)
void layer_mfma_kernel(const _Float16* __restrict__ agg,
                       const _Float16* __restrict__ xin,
                       const _Float16* __restrict__ wt,
                       const float* __restrict__ bias,
                       _Float16* __restrict__ out, int N) {
    __shared__ _Float16 s_a[64][LK];   // 33792 B

    const int tid = threadIdx.x;
    const int nb = blockIdx.x * 64;

    for (int i = tid; i < 64 * 32; i += 256) {
        int r = i >> 5;
        int c8 = (i & 31) << 3;
        int gn = nb + r;
        f16x8 v = {};
        if (gn < N) {
            const _Float16* srcp = (c8 < 128) ? &agg[(size_t)gn * CH + c8]
                                              : &xin[(size_t)gn * CH + (c8 - 128)];
            v = *(const f16x8*)srcp;
        }
        *(f16x8*)&s_a[r][c8] = v;
    }
    __syncthreads();

    const int wave = tid >> 6;
    const int lane = tid & 63;
    const int quad = lane >> 4;
    const int l16  = lane & 15;

    f32x4 acc[4][2];
#pragma unroll
    for (int m = 0; m < 4; m++)
#pragma unroll
        for (int t = 0; t < 2; t++) acc[m][t] = (f32x4){0.f, 0.f, 0.f, 0.f};

    const int kq = quad * 8;

#pragma unroll
    for (int ks = 0; ks < 8; ks++) {
        int kbase = ks * 32 + kq;
        f16x8 bf[2];
#pragma unroll
        for (int t = 0; t < 2; t++) {
            int n = wave * 32 + t * 16 + l16;
            bf[t] = *(const f16x8*)&wt[(size_t)n * 256 + kbase];
        }
#pragma unroll
        for (int m = 0; m < 4; m++) {
            f16x8 af = *(const f16x8*)&s_a[m * 16 + l16][kbase];
            acc[m][0] = __builtin_amdgcn_mfma_f32_16x16x32_f16(af, bf[0], acc[m][0], 0, 0, 0);
            acc[m][1] = __builtin_amdgcn_mfma_f32_16x16x32_f16(af, bf[1], acc[m][1], 0, 0, 0);
        }
    }

    float bv[2];
    bv[0] = bias[wave * 32 + l16];
    bv[1] = bias[wave * 32 + 16 + l16];

#pragma unroll
    for (int m = 0; m < 4; m++) {
#pragma unroll
        for (int r = 0; r < 4; r++) {
            int node = nb + m * 16 + quad * 4 + r;
            if (node >= N) continue;
#pragma unroll
            for (int t = 0; t < 2; t++) {
                float v = acc[m][t][r] + bv[t];
                if (RELU) v = fmaxf(v, 0.f);
                out[(size_t)node * CH + wave * 32 + t * 16 + l16] = (_Float16)v;
            }
        }
    }
}

// ---- decode: one wave per pair, fp16 z ----
__global__ void decode_kernel(const _Float16* __restrict__ z,
                              const int* __restrict__ ps,
                              const int* __restrict__ pd,
                              float* __restrict__ out, int P) {
    long tid = (long)blockIdx.x * blockDim.x + threadIdx.x;
    int p = (int)(tid >> 6);
    int lane = (int)(tid & 63);
    if (p >= P) return;
    int s = ps[p], d = pd[p];
    f16x2 a = *(const f16x2*)&z[(size_t)s * CH + lane * 2];
    f16x2 b = *(const f16x2*)&z[(size_t)d * CH + lane * 2];
    float v = (float)a[0] * (float)b[0] + (float)a[1] * (float)b[1];
#pragma unroll
    for (int off = 32; off > 0; off >>= 1) v += __shfl_down(v, off, 64);
    if (lane == 0) out[p] = v * 0.08838834764831845f;  // 1/sqrt(128)
}

extern "C" void kernel_launch(void* const* d_in, const int* in_sizes, int n_in,
                              void* d_out, int out_size, void* d_ws, size_t ws_size,
                              hipStream_t stream) {
    const float* x       = (const float*)d_in[0];
    const int*   ei      = (const int*)d_in[1];   // [2, E]: src then dst
    const float* ew      = (const float*)d_in[2];
    const int*   eli     = (const int*)d_in[3];   // [2, P]
    const float* w1_rel  = (const float*)d_in[4];
    const float* b1      = (const float*)d_in[5];
    const float* w1_root = (const float*)d_in[6];
    const float* w2_rel  = (const float*)d_in[7];
    const float* b2      = (const float*)d_in[8];
    const float* w2_root = (const float*)d_in[9];
    float* out = (float*)d_out;

    const int N = NN, E = NE, P = NP;
    const size_t hrow = (size_t)N * CH * sizeof(_Float16);   // 25.6 MB

    char* ws = (char*)d_ws;
    size_t off = 0;
    auto alloc = [&](size_t bytes) { char* p = ws + off; off = (off + bytes + 15) & ~(size_t)15; return p; };
    _Float16* xh   = (_Float16*)alloc(hrow);
    _Float16* aggh = (_Float16*)alloc(hrow);
    _Float16* hh   = (_Float16*)alloc(hrow);
    _Float16* zh   = aggh;                  // alias: block reads its rows before writing
    int* cnt      = (int*)alloc((size_t)N * CPAD * 4);   // padded: 6.4 MB
    int* row_ptr  = (int*)alloc((size_t)(N + 1) * 4);
    int* partials = (int*)alloc(256 * 4);
    int* rank     = (int*)alloc((size_t)E * 4);
    int2* csr     = (int2*)alloc((size_t)E * 8);
    _Float16* w1t = (_Float16*)alloc((size_t)128 * 256 * 2);
    _Float16* w2t = (_Float16*)alloc((size_t)128 * 256 * 2);

    const int* src = ei;
    const int* dst = ei + E;

    const int nb_scan = (N + SB - 1) / SB;  // 98
    const int n8 = N * CH / 8;              // 1.6M

    // --- prep: cast x, transpose weights ---
    cast_kernel<<<(n8 + 255) / 256, 256, 0, stream>>>(x, xh, n8);
    prep_w_kernel<<<128, 256, 0, stream>>>(w1_rel, w1_root, w1t);
    prep_w_kernel<<<128, 256, 0, stream>>>(w2_rel, w2_root, w2t);

    // --- CSR build ---
    hipMemsetAsync(cnt, 0, (size_t)N * CPAD * 4, stream);
    {
        int nthr = E / 8;   // 200K threads, 8 edges each
        count_rank_kernel<<<(nthr + 255) / 256, 256, 0, stream>>>(dst, cnt, rank, E);
    }
    scan1_kernel<<<nb_scan, SB, 0, stream>>>(cnt, row_ptr, partials, N);
    scan2_kernel<<<1, 128, 0, stream>>>(partials, nb_scan);
    scan3_kernel<<<nb_scan, SB, 0, stream>>>(row_ptr, partials, N);
    fill_kernel<<<(E + 255) / 256, 256, 0, stream>>>(src, dst, ew, row_ptr, rank, csr, E);

    // --- layer 1 ---
    gather_kernel<<<(N + 3) / 4, 256, 0, stream>>>(xh, row_ptr, csr, aggh, N);
    layer_mfma_kernel<true><<<(N + 63) / 64, 256, 0, stream>>>(aggh, xh, w1t, b1, hh, N);

    // --- layer 2 ---
    gather_kernel<<<(N + 3) / 4, 256, 0, stream>>>(hh, row_ptr, csr, aggh, N);
    layer_mfma_kernel<false><<<(N + 63) / 64, 256, 0, stream>>>(aggh, hh, w2t, b2, zh, N);

    // --- decode ---
    {
        long threads = (long)P * 64;
        decode_kernel<<<(int)((threads + 255) / 256), 256, 0, stream>>>(zh, eli, eli + P, out, P);
    }
}

// Round 6
// 410.326 us; speedup vs baseline: 14.1909x; 1.0719x over previous
//
#include <hip/hip_runtime.h>

#define NN 100000
#define NE 1600000
#define NP 200000
#define CH 128
#define LK 264    // padded LDS row stride (fp16 elems)

#define BSH 6                    // 64 nodes per bucket
#define NB  1563                 // ceil(NN / 64)
#define G1  256                  // pass1/pass2 grid
#define EPB (NE / G1)            // 6250 edges per block (divides exactly)
#define CAP3 4096                // pass3 LDS edge capacity (mean bucket = 1024)

typedef _Float16 f16x8 __attribute__((ext_vector_type(8)));
typedef _Float16 f16x2 __attribute__((ext_vector_type(2)));
typedef float f32x4 __attribute__((ext_vector_type(4)));

// ---- fp32 -> fp16 row cast ----
__global__ void cast_kernel(const float* __restrict__ in, _Float16* __restrict__ out, int n8) {
    int i = blockIdx.x * blockDim.x + threadIdx.x;
    if (i >= n8) return;
    const float4* p = (const float4*)in + (size_t)i * 2;
    float4 a = p[0], b = p[1];
    f16x8 o = { (_Float16)a.x, (_Float16)a.y, (_Float16)a.z, (_Float16)a.w,
                (_Float16)b.x, (_Float16)b.y, (_Float16)b.z, (_Float16)b.w };
    *((f16x8*)out + i) = o;
}

// ---- CSR pass 1: per-block bucket histogram (LDS atomics only) ----
__global__ __launch_bounds__(256)
void bucket_hist_kernel(const int* __restrict__ dst, int* __restrict__ hist /*[G1][NB]*/) {
    __shared__ int s_h[NB];
    for (int i = threadIdx.x; i < NB; i += 256) s_h[i] = 0;
    __syncthreads();
    int start = blockIdx.x * EPB, end = start + EPB;
    for (int e = start + threadIdx.x; e < end; e += 256)
        atomicAdd(&s_h[dst[e] >> BSH], 1);
    __syncthreads();
    int* row = hist + (size_t)blockIdx.x * NB;
    for (int i = threadIdx.x; i < NB; i += 256) row[i] = s_h[i];
}

// ---- CSR pass 1b: column exclusive scan over g (thread per bucket, coalesced) ----
__global__ void colscan_kernel(int* __restrict__ hist, int* __restrict__ totals) {
    int b = blockIdx.x * blockDim.x + threadIdx.x;
    if (b >= NB) return;
    int run = 0;
    for (int g = 0; g < G1; g++) {
        size_t idx = (size_t)g * NB + b;
        int v = hist[idx];
        hist[idx] = run;
        run += v;
    }
    totals[b] = run;
}

// ---- CSR pass 1c: exclusive scan of bucket totals -> base[NB+1] (single block) ----
__global__ __launch_bounds__(1024)
void scanB_kernel(const int* __restrict__ totals, int* __restrict__ base) {
    __shared__ int s[2048];
    int tid = threadIdx.x;
    for (int i = tid; i < 2048; i += 1024) s[i] = (i < NB) ? totals[i] : 0;
    __syncthreads();
    for (int off = 1; off < 2048; off <<= 1) {
        int i0 = tid, i1 = tid + 1024;
        int v0 = (i0 >= off) ? s[i0 - off] : 0;
        int v1 = (i1 >= off) ? s[i1 - off] : 0;
        __syncthreads();
        s[i0] += v0; s[i1] += v1;
        __syncthreads();
    }
    if (tid == 0) base[0] = 0;
    for (int i = tid; i < NB; i += 1024) base[i + 1] = s[i];
}

// ---- CSR pass 2: scatter edges into bucket regions via LDS cursors ----
// packed.x = src | (dst_local << 17); packed.y = weight bits
__global__ __launch_bounds__(256)
void bucket_scatter_kernel(const int* __restrict__ src, const int* __restrict__ dst,
                           const float* __restrict__ ew, const int* __restrict__ hist,
                           const int* __restrict__ base, int2* __restrict__ tmp) {
    __shared__ int s_cur[NB];
    const int* row = hist + (size_t)blockIdx.x * NB;
    for (int i = threadIdx.x; i < NB; i += 256) s_cur[i] = base[i] + row[i];
    __syncthreads();
    int start = blockIdx.x * EPB, end = start + EPB;
    for (int e = start + threadIdx.x; e < end; e += 256) {
        int d = dst[e];
        int b = d >> BSH;
        int pos = atomicAdd(&s_cur[b], 1);
        tmp[pos] = make_int2(src[e] | ((d & 63) << 17), __float_as_int(ew[e]));
    }
}

// ---- CSR pass 3: per-bucket finalize -> row_ptr + node-grouped csr ----
__global__ __launch_bounds__(256)
void bucket_finalize_kernel(const int2* __restrict__ tmp, const int* __restrict__ base,
                            int* __restrict__ row_ptr, int2* __restrict__ csr, int N) {
    __shared__ int2 s_e[CAP3];
    __shared__ int s_cnt[64], s_off[64];
    int b = blockIdx.x;
    int lo = base[b], hi = base[b + 1];
    int size = hi - lo;
    int nbase = b << BSH;
    int ncnt = min(64, N - nbase);
    int tid = threadIdx.x;
    if (tid < 64) s_cnt[tid] = 0;
    bool inlds = (size <= CAP3);
    __syncthreads();
    if (inlds) {
        for (int i = tid; i < size; i += 256) {
            int2 e = tmp[lo + i];
            s_e[i] = e;
            atomicAdd(&s_cnt[(e.x >> 17) & 63], 1);
        }
    } else {
        for (int i = tid; i < size; i += 256) {
            int2 e = tmp[lo + i];
            atomicAdd(&s_cnt[(e.x >> 17) & 63], 1);
        }
    }
    __syncthreads();
    if (tid == 0) {
        int run = 0;
        for (int i = 0; i < 64; i++) { int v = s_cnt[i]; s_off[i] = run; s_cnt[i] = run; run += v; }
    }
    __syncthreads();
    if (tid < ncnt) row_ptr[nbase + tid] = lo + s_off[tid];
    if (b == NB - 1 && tid == 0) row_ptr[N] = hi;
    if (inlds) {
        for (int i = tid; i < size; i += 256) {
            int2 e = s_e[i];
            int dl = (e.x >> 17) & 63;
            int p = atomicAdd(&s_cnt[dl], 1);
            csr[lo + p] = make_int2(e.x & 0x1FFFF, e.y);
        }
    } else {
        for (int i = tid; i < size; i += 256) {
            int2 e = tmp[lo + i];
            int dl = (e.x >> 17) & 63;
            int p = atomicAdd(&s_cnt[dl], 1);
            csr[lo + p] = make_int2(e.x & 0x1FFFF, e.y);
        }
    }
}

// ---- gather-aggregate (mean folded): one wave per node, 4 edges in flight,
//      2-deep software pipeline per quarter ----
__global__ __launch_bounds__(256)
void gather_kernel(const _Float16* __restrict__ feat, const int* __restrict__ row_ptr,
                   const int2* __restrict__ csr, _Float16* __restrict__ agg, int N) {
    int node = blockIdx.x * 4 + (threadIdx.x >> 6);
    if (node >= N) return;
    int lane = threadIdx.x & 63;
    int q = lane >> 4;
    int l16 = lane & 15;
    int c8 = l16 << 3;
    int r0 = row_ptr[node], r1 = row_ptr[node + 1];
    float acc[8] = {0.f, 0.f, 0.f, 0.f, 0.f, 0.f, 0.f, 0.f};
    int r = r0 + q;
    if (r < r1) {
        int2 e = csr[r];
        f16x8 v = *(const f16x8*)&feat[(size_t)e.x * CH + c8];
        for (r += 4; r < r1; r += 4) {
            int2 e2 = csr[r];
            f16x8 v2 = *(const f16x8*)&feat[(size_t)e2.x * CH + c8];
            float w = __int_as_float(e.y);
#pragma unroll
            for (int j = 0; j < 8; j++) acc[j] += w * (float)v[j];
            e = e2; v = v2;
        }
        float w = __int_as_float(e.y);
#pragma unroll
        for (int j = 0; j < 8; j++) acc[j] += w * (float)v[j];
    }
#pragma unroll
    for (int j = 0; j < 8; j++) {
        acc[j] += __shfl_xor(acc[j], 16, 64);
        acc[j] += __shfl_xor(acc[j], 32, 64);
    }
    if (q == 0) {
        float inv = 1.0f / fmaxf((float)(r1 - r0), 1.0f);
        f16x8 o;
#pragma unroll
        for (int j = 0; j < 8; j++) o[j] = (_Float16)(acc[j] * inv);
        *(f16x8*)&agg[(size_t)node * CH + c8] = o;
    }
}

// ---- weight prep: Wt[n][k] fp16, k<128 -> w_rel, else w_root ----
__global__ void prep_w_kernel(const float* __restrict__ wr, const float* __restrict__ wo,
                              _Float16* __restrict__ wt) {
    int idx = blockIdx.x * 256 + threadIdx.x;
    if (idx >= 128 * 256) return;
    int n = idx >> 8, k = idx & 255;
    float v = (k < 128) ? wr[k * 128 + n] : wo[(k - 128) * 128 + n];
    wt[idx] = (_Float16)v;
}

// ---- MFMA layer: out[n x 128] = [agg | xin] @ Wt^T + b  (optional relu), fp16 in/out ----
template <bool RELU>
__global__ __launch_bounds__(256)
void layer_mfma_kernel(const _Float16* __restrict__ agg,
                       const _Float16* __restrict__ xin,
                       const _Float16* __restrict__ wt,
                       const float* __restrict__ bias,
                       _Float16* __restrict__ out, int N) {
    __shared__ _Float16 s_a[64][LK];   // 33792 B

    const int tid = threadIdx.x;
    const int nb = blockIdx.x * 64;

    for (int i = tid; i < 64 * 32; i += 256) {
        int r = i >> 5;
        int c8 = (i & 31) << 3;
        int gn = nb + r;
        f16x8 v = {};
        if (gn < N) {
            const _Float16* srcp = (c8 < 128) ? &agg[(size_t)gn * CH + c8]
                                              : &xin[(size_t)gn * CH + (c8 - 128)];
            v = *(const f16x8*)srcp;
        }
        *(f16x8*)&s_a[r][c8] = v;
    }
    __syncthreads();

    const int wave = tid >> 6;
    const int lane = tid & 63;
    const int quad = lane >> 4;
    const int l16  = lane & 15;

    f32x4 acc[4][2];
#pragma unroll
    for (int m = 0; m < 4; m++)
#pragma unroll
        for (int t = 0; t < 2; t++) acc[m][t] = (f32x4){0.f, 0.f, 0.f, 0.f};

    const int kq = quad * 8;

#pragma unroll
    for (int ks = 0; ks < 8; ks++) {
        int kbase = ks * 32 + kq;
        f16x8 bf[2];
#pragma unroll
        for (int t = 0; t < 2; t++) {
            int n = wave * 32 + t * 16 + l16;
            bf[t] = *(const f16x8*)&wt[(size_t)n * 256 + kbase];
        }
#pragma unroll
        for (int m = 0; m < 4; m++) {
            f16x8 af = *(const f16x8*)&s_a[m * 16 + l16][kbase];
            acc[m][0] = __builtin_amdgcn_mfma_f32_16x16x32_f16(af, bf[0], acc[m][0], 0, 0, 0);
            acc[m][1] = __builtin_amdgcn_mfma_f32_16x16x32_f16(af, bf[1], acc[m][1], 0, 0, 0);
        }
    }

    float bv[2];
    bv[0] = bias[wave * 32 + l16];
    bv[1] = bias[wave * 32 + 16 + l16];

#pragma unroll
    for (int m = 0; m < 4; m++) {
#pragma unroll
        for (int r = 0; r < 4; r++) {
            int node = nb + m * 16 + quad * 4 + r;
            if (node >= N) continue;
#pragma unroll
            for (int t = 0; t < 2; t++) {
                float v = acc[m][t][r] + bv[t];
                if (RELU) v = fmaxf(v, 0.f);
                out[(size_t)node * CH + wave * 32 + t * 16 + l16] = (_Float16)v;
            }
        }
    }
}

// ---- decode: one wave per pair, fp16 z ----
__global__ void decode_kernel(const _Float16* __restrict__ z,
                              const int* __restrict__ ps,
                              const int* __restrict__ pd,
                              float* __restrict__ out, int P) {
    long tid = (long)blockIdx.x * blockDim.x + threadIdx.x;
    int p = (int)(tid >> 6);
    int lane = (int)(tid & 63);
    if (p >= P) return;
    int s = ps[p], d = pd[p];
    f16x2 a = *(const f16x2*)&z[(size_t)s * CH + lane * 2];
    f16x2 b = *(const f16x2*)&z[(size_t)d * CH + lane * 2];
    float v = (float)a[0] * (float)b[0] + (float)a[1] * (float)b[1];
#pragma unroll
    for (int off = 32; off > 0; off >>= 1) v += __shfl_down(v, off, 64);
    if (lane == 0) out[p] = v * 0.08838834764831845f;  // 1/sqrt(128)
}

extern "C" void kernel_launch(void* const* d_in, const int* in_sizes, int n_in,
                              void* d_out, int out_size, void* d_ws, size_t ws_size,
                              hipStream_t stream) {
    const float* x       = (const float*)d_in[0];
    const int*   ei      = (const int*)d_in[1];   // [2, E]: src then dst
    const float* ew      = (const float*)d_in[2];
    const int*   eli     = (const int*)d_in[3];   // [2, P]
    const float* w1_rel  = (const float*)d_in[4];
    const float* b1      = (const float*)d_in[5];
    const float* w1_root = (const float*)d_in[6];
    const float* w2_rel  = (const float*)d_in[7];
    const float* b2      = (const float*)d_in[8];
    const float* w2_root = (const float*)d_in[9];
    float* out = (float*)d_out;

    const int N = NN, E = NE, P = NP;
    const size_t hrow = (size_t)N * CH * sizeof(_Float16);   // 25.6 MB

    char* ws = (char*)d_ws;
    size_t off = 0;
    auto alloc = [&](size_t bytes) { char* p = ws + off; off = (off + bytes + 15) & ~(size_t)15; return p; };
    _Float16* xh   = (_Float16*)alloc(hrow);
    _Float16* aggh = (_Float16*)alloc(hrow);
    _Float16* hh   = (_Float16*)alloc(hrow);
    _Float16* zh   = aggh;                  // alias: block reads its rows before writing
    int* hist     = (int*)alloc((size_t)G1 * NB * 4);    // 1.6 MB
    int* totals   = (int*)alloc((size_t)NB * 4);
    int* base     = (int*)alloc((size_t)(NB + 1) * 4);
    int* row_ptr  = (int*)alloc((size_t)(N + 1) * 4);
    int2* tmp     = (int2*)alloc((size_t)E * 8);         // 12.8 MB
    int2* csr     = (int2*)alloc((size_t)E * 8);         // 12.8 MB
    _Float16* w1t = (_Float16*)alloc((size_t)128 * 256 * 2);
    _Float16* w2t = (_Float16*)alloc((size_t)128 * 256 * 2);

    const int* src = ei;
    const int* dst = ei + E;

    const int n8 = N * CH / 8;              // 1.6M

    // --- prep: cast x, transpose weights ---
    cast_kernel<<<(n8 + 255) / 256, 256, 0, stream>>>(x, xh, n8);
    prep_w_kernel<<<128, 256, 0, stream>>>(w1_rel, w1_root, w1t);
    prep_w_kernel<<<128, 256, 0, stream>>>(w2_rel, w2_root, w2t);

    // --- CSR build (atomic-free bucketed counting sort) ---
    bucket_hist_kernel<<<G1, 256, 0, stream>>>(dst, hist);
    colscan_kernel<<<(NB + 255) / 256, 256, 0, stream>>>(hist, totals);
    scanB_kernel<<<1, 1024, 0, stream>>>(totals, base);
    bucket_scatter_kernel<<<G1, 256, 0, stream>>>(src, dst, ew, hist, base, tmp);
    bucket_finalize_kernel<<<NB, 256, 0, stream>>>(tmp, base, row_ptr, csr, N);

    // --- layer 1 ---
    gather_kernel<<<(N + 3) / 4, 256, 0, stream>>>(xh, row_ptr, csr, aggh, N);
    layer_mfma_kernel<true><<<(N + 63) / 64, 256, 0, stream>>>(aggh, xh, w1t, b1, hh, N);

    // --- layer 2 ---
    gather_kernel<<<(N + 3) / 4, 256, 0, stream>>>(hh, row_ptr, csr, aggh, N);
    layer_mfma_kernel<false><<<(N + 63) / 64, 256, 0, stream>>>(aggh, hh, w2t, b2, zh, N);

    // --- decode ---
    {
        long threads = (long)P * 64;
        decode_kernel<<<(int)((threads + 255) / 256), 256, 0, stream>>>(zh, eli, eli + P, out, P);
    }
}

// Round 7
// 387.397 us; speedup vs baseline: 15.0308x; 1.0592x over previous
//
#include <hip/hip_runtime.h>

#define NN 100000
#define NE 1600000
#define NP 200000
#define CH 128
#define LK 264    // padded LDS row stride (fp16 elems)

#define BSH 6                    // 64 nodes per bucket
#define NB  1563                 // ceil(NN / 64)
#define G1  256                  // pass1/pass2 grid
#define EPB (NE / G1)            // 6250 edges per block (divides exactly)
#define CAP3 4096                // pass3 LDS edge capacity (mean bucket = 1024)

typedef _Float16 f16x8 __attribute__((ext_vector_type(8)));
typedef _Float16 f16x4 __attribute__((ext_vector_type(4)));
typedef float f32x4 __attribute__((ext_vector_type(4)));

// ---- fp32 -> fp16 row cast ----
__global__ void cast_kernel(const float* __restrict__ in, _Float16* __restrict__ out, int n8) {
    int i = blockIdx.x * blockDim.x + threadIdx.x;
    if (i >= n8) return;
    const float4* p = (const float4*)in + (size_t)i * 2;
    float4 a = p[0], b = p[1];
    f16x8 o = { (_Float16)a.x, (_Float16)a.y, (_Float16)a.z, (_Float16)a.w,
                (_Float16)b.x, (_Float16)b.y, (_Float16)b.z, (_Float16)b.w };
    *((f16x8*)out + i) = o;
}

// ---- CSR pass 1: per-block bucket histogram (LDS atomics only) ----
__global__ __launch_bounds__(256)
void bucket_hist_kernel(const int* __restrict__ dst, int* __restrict__ hist /*[G1][NB]*/) {
    __shared__ int s_h[NB];
    for (int i = threadIdx.x; i < NB; i += 256) s_h[i] = 0;
    __syncthreads();
    int start = blockIdx.x * EPB, end = start + EPB;
    for (int e = start + threadIdx.x; e < end; e += 256)
        atomicAdd(&s_h[dst[e] >> BSH], 1);
    __syncthreads();
    int* row = hist + (size_t)blockIdx.x * NB;
    for (int i = threadIdx.x; i < NB; i += 256) row[i] = s_h[i];
}

// ---- CSR pass 1b: column exclusive scan over g — ONE WAVE PER BUCKET ----
// lane L holds g = 4L..4L+3; local prefix + shfl_up wave scan
__global__ __launch_bounds__(256)
void colscan_kernel(int* __restrict__ hist, int* __restrict__ totals) {
    int b = blockIdx.x * 4 + (threadIdx.x >> 6);
    if (b >= NB) return;
    int lane = threadIdx.x & 63;
    size_t base = (size_t)(lane * 4) * NB + b;
    int v0 = hist[base];
    int v1 = hist[base + NB];
    int v2 = hist[base + 2 * (size_t)NB];
    int v3 = hist[base + 3 * (size_t)NB];
    int s0 = v0, s1 = s0 + v1, s2 = s1 + v2, s3 = s2 + v3;
    int incl = s3;
#pragma unroll
    for (int off = 1; off < 64; off <<= 1) {
        int n = __shfl_up(incl, off, 64);
        if (lane >= off) incl += n;
    }
    int excl = incl - s3;
    hist[base] = excl;
    hist[base + NB] = excl + s0;
    hist[base + 2 * (size_t)NB] = excl + s1;
    hist[base + 3 * (size_t)NB] = excl + s2;
    if (lane == 63) totals[b] = incl;
}

// ---- CSR pass 1c: exclusive scan of bucket totals -> base[NB+1] (single block) ----
__global__ __launch_bounds__(1024)
void scanB_kernel(const int* __restrict__ totals, int* __restrict__ base) {
    __shared__ int s[2048];
    int tid = threadIdx.x;
    for (int i = tid; i < 2048; i += 1024) s[i] = (i < NB) ? totals[i] : 0;
    __syncthreads();
    for (int off = 1; off < 2048; off <<= 1) {
        int i0 = tid, i1 = tid + 1024;
        int v0 = (i0 >= off) ? s[i0 - off] : 0;
        int v1 = (i1 >= off) ? s[i1 - off] : 0;
        __syncthreads();
        s[i0] += v0; s[i1] += v1;
        __syncthreads();
    }
    if (tid == 0) base[0] = 0;
    for (int i = tid; i < NB; i += 1024) base[i + 1] = s[i];
}

// ---- CSR pass 2: scatter edges into bucket regions via LDS cursors ----
// packed.x = src | (dst_local << 17); packed.y = weight bits
__global__ __launch_bounds__(256)
void bucket_scatter_kernel(const int* __restrict__ src, const int* __restrict__ dst,
                           const float* __restrict__ ew, const int* __restrict__ hist,
                           const int* __restrict__ base, int2* __restrict__ tmp) {
    __shared__ int s_cur[NB];
    const int* row = hist + (size_t)blockIdx.x * NB;
    for (int i = threadIdx.x; i < NB; i += 256) s_cur[i] = base[i] + row[i];
    __syncthreads();
    int start = blockIdx.x * EPB, end = start + EPB;
    for (int e = start + threadIdx.x; e < end; e += 256) {
        int d = dst[e];
        int b = d >> BSH;
        int pos = atomicAdd(&s_cur[b], 1);
        tmp[pos] = make_int2(src[e] | ((d & 63) << 17), __float_as_int(ew[e]));
    }
}

// ---- CSR pass 3: per-bucket finalize -> row_ptr + node-grouped csr ----
__global__ __launch_bounds__(256)
void bucket_finalize_kernel(const int2* __restrict__ tmp, const int* __restrict__ base,
                            int* __restrict__ row_ptr, int2* __restrict__ csr, int N) {
    __shared__ int2 s_e[CAP3];
    __shared__ int s_cnt[64], s_off[64];
    int b = blockIdx.x;
    int lo = base[b], hi = base[b + 1];
    int size = hi - lo;
    int nbase = b << BSH;
    int ncnt = min(64, N - nbase);
    int tid = threadIdx.x;
    if (tid < 64) s_cnt[tid] = 0;
    bool inlds = (size <= CAP3);
    __syncthreads();
    if (inlds) {
        for (int i = tid; i < size; i += 256) {
            int2 e = tmp[lo + i];
            s_e[i] = e;
            atomicAdd(&s_cnt[(e.x >> 17) & 63], 1);
        }
    } else {
        for (int i = tid; i < size; i += 256) {
            int2 e = tmp[lo + i];
            atomicAdd(&s_cnt[(e.x >> 17) & 63], 1);
        }
    }
    __syncthreads();
    if (tid == 0) {
        int run = 0;
        for (int i = 0; i < 64; i++) { int v = s_cnt[i]; s_off[i] = run; s_cnt[i] = run; run += v; }
    }
    __syncthreads();
    if (tid < ncnt) row_ptr[nbase + tid] = lo + s_off[tid];
    if (b == NB - 1 && tid == 0) row_ptr[N] = hi;
    if (inlds) {
        for (int i = tid; i < size; i += 256) {
            int2 e = s_e[i];
            int dl = (e.x >> 17) & 63;
            int p = atomicAdd(&s_cnt[dl], 1);
            csr[lo + p] = make_int2(e.x & 0x1FFFF, e.y);
        }
    } else {
        for (int i = tid; i < size; i += 256) {
            int2 e = tmp[lo + i];
            int dl = (e.x >> 17) & 63;
            int p = atomicAdd(&s_cnt[dl], 1);
            csr[lo + p] = make_int2(e.x & 0x1FFFF, e.y);
        }
    }
}

// ---- gather-aggregate (mean folded): one wave per node, 4 edges in flight,
//      2-deep software pipeline per quarter ----
__global__ __launch_bounds__(256)
void gather_kernel(const _Float16* __restrict__ feat, const int* __restrict__ row_ptr,
                   const int2* __restrict__ csr, _Float16* __restrict__ agg, int N) {
    int node = blockIdx.x * 4 + (threadIdx.x >> 6);
    if (node >= N) return;
    int lane = threadIdx.x & 63;
    int q = lane >> 4;
    int l16 = lane & 15;
    int c8 = l16 << 3;
    int r0 = row_ptr[node], r1 = row_ptr[node + 1];
    float acc[8] = {0.f, 0.f, 0.f, 0.f, 0.f, 0.f, 0.f, 0.f};
    int r = r0 + q;
    if (r < r1) {
        int2 e = csr[r];
        f16x8 v = *(const f16x8*)&feat[(size_t)e.x * CH + c8];
        for (r += 4; r < r1; r += 4) {
            int2 e2 = csr[r];
            f16x8 v2 = *(const f16x8*)&feat[(size_t)e2.x * CH + c8];
            float w = __int_as_float(e.y);
#pragma unroll
            for (int j = 0; j < 8; j++) acc[j] += w * (float)v[j];
            e = e2; v = v2;
        }
        float w = __int_as_float(e.y);
#pragma unroll
        for (int j = 0; j < 8; j++) acc[j] += w * (float)v[j];
    }
#pragma unroll
    for (int j = 0; j < 8; j++) {
        acc[j] += __shfl_xor(acc[j], 16, 64);
        acc[j] += __shfl_xor(acc[j], 32, 64);
    }
    if (q == 0) {
        float inv = 1.0f / fmaxf((float)(r1 - r0), 1.0f);
        f16x8 o;
#pragma unroll
        for (int j = 0; j < 8; j++) o[j] = (_Float16)(acc[j] * inv);
        *(f16x8*)&agg[(size_t)node * CH + c8] = o;
    }
}

// ---- weight prep (both layers fused): Wt[n][k] fp16, k<128 -> w_rel, else w_root ----
__global__ void prep_w2_kernel(const float* __restrict__ w1r, const float* __restrict__ w1o,
                               const float* __restrict__ w2r, const float* __restrict__ w2o,
                               _Float16* __restrict__ w1t, _Float16* __restrict__ w2t) {
    int idx = blockIdx.x * 256 + threadIdx.x;
    if (idx >= 2 * 128 * 256) return;
    int which = idx >> 15;
    int li = idx & 32767;
    int n = li >> 8, k = li & 255;
    const float* wr = which ? w2r : w1r;
    const float* wo = which ? w2o : w1o;
    _Float16* wt = which ? w2t : w1t;
    float v = (k < 128) ? wr[k * 128 + n] : wo[(k - 128) * 128 + n];
    wt[li] = (_Float16)v;
}

// ---- MFMA layer: out[n x 128] = [agg | xin] @ Wt^T + b  (optional relu), fp16 in/out ----
template <bool RELU>
__global__ __launch_bounds__(256)
void layer_mfma_kernel(const _Float16* __restrict__ agg,
                       const _Float16* __restrict__ xin,
                       const _Float16* __restrict__ wt,
                       const float* __restrict__ bias,
                       _Float16* __restrict__ out, int N) {
    __shared__ _Float16 s_a[64][LK];   // 33792 B

    const int tid = threadIdx.x;
    const int nb = blockIdx.x * 64;

    for (int i = tid; i < 64 * 32; i += 256) {
        int r = i >> 5;
        int c8 = (i & 31) << 3;
        int gn = nb + r;
        f16x8 v = {};
        if (gn < N) {
            const _Float16* srcp = (c8 < 128) ? &agg[(size_t)gn * CH + c8]
                                              : &xin[(size_t)gn * CH + (c8 - 128)];
            v = *(const f16x8*)srcp;
        }
        *(f16x8*)&s_a[r][c8] = v;
    }
    __syncthreads();

    const int wave = tid >> 6;
    const int lane = tid & 63;
    const int quad = lane >> 4;
    const int l16  = lane & 15;

    f32x4 acc[4][2];
#pragma unroll
    for (int m = 0; m < 4; m++)
#pragma unroll
        for (int t = 0; t < 2; t++) acc[m][t] = (f32x4){0.f, 0.f, 0.f, 0.f};

    const int kq = quad * 8;

#pragma unroll
    for (int ks = 0; ks < 8; ks++) {
        int kbase = ks * 32 + kq;
        f16x8 bf[2];
#pragma unroll
        for (int t = 0; t < 2; t++) {
            int n = wave * 32 + t * 16 + l16;
            bf[t] = *(const f16x8*)&wt[(size_t)n * 256 + kbase];
        }
#pragma unroll
        for (int m = 0; m < 4; m++) {
            f16x8 af = *(const f16x8*)&s_a[m * 16 + l16][kbase];
            acc[m][0] = __builtin_amdgcn_mfma_f32_16x16x32_f16(af, bf[0], acc[m][0], 0, 0, 0);
            acc[m][1] = __builtin_amdgcn_mfma_f32_16x16x32_f16(af, bf[1], acc[m][1], 0, 0, 0);
        }
    }

    float bv[2];
    bv[0] = bias[wave * 32 + l16];
    bv[1] = bias[wave * 32 + 16 + l16];

#pragma unroll
    for (int m = 0; m < 4; m++) {
#pragma unroll
        for (int r = 0; r < 4; r++) {
            int node = nb + m * 16 + quad * 4 + r;
            if (node >= N) continue;
#pragma unroll
            for (int t = 0; t < 2; t++) {
                float v = acc[m][t][r] + bv[t];
                if (RELU) v = fmaxf(v, 0.f);
                out[(size_t)node * CH + wave * 32 + t * 16 + l16] = (_Float16)v;
            }
        }
    }
}

// ---- decode: HALF-wave per pair, f16x4 per lane (32 x 8 B = one 256 B row) ----
__global__ void decode_kernel(const _Float16* __restrict__ z,
                              const int* __restrict__ ps,
                              const int* __restrict__ pd,
                              float* __restrict__ out, int P) {
    long tid = (long)blockIdx.x * blockDim.x + threadIdx.x;
    int p = (int)(tid >> 5);
    int lane = (int)(tid & 31);
    if (p >= P) return;
    int s = ps[p], d = pd[p];
    f16x4 a = *(const f16x4*)&z[(size_t)s * CH + lane * 4];
    f16x4 b = *(const f16x4*)&z[(size_t)d * CH + lane * 4];
    float v = (float)a[0] * (float)b[0] + (float)a[1] * (float)b[1]
            + (float)a[2] * (float)b[2] + (float)a[3] * (float)b[3];
#pragma unroll
    for (int off = 16; off > 0; off >>= 1) v += __shfl_xor(v, off, 64);
    if (lane == 0) out[p] = v * 0.08838834764831845f;  // 1/sqrt(128)
}

extern "C" void kernel_launch(void* const* d_in, const int* in_sizes, int n_in,
                              void* d_out, int out_size, void* d_ws, size_t ws_size,
                              hipStream_t stream) {
    const float* x       = (const float*)d_in[0];
    const int*   ei      = (const int*)d_in[1];   // [2, E]: src then dst
    const float* ew      = (const float*)d_in[2];
    const int*   eli     = (const int*)d_in[3];   // [2, P]
    const float* w1_rel  = (const float*)d_in[4];
    const float* b1      = (const float*)d_in[5];
    const float* w1_root = (const float*)d_in[6];
    const float* w2_rel  = (const float*)d_in[7];
    const float* b2      = (const float*)d_in[8];
    const float* w2_root = (const float*)d_in[9];
    float* out = (float*)d_out;

    const int N = NN, E = NE, P = NP;
    const size_t hrow = (size_t)N * CH * sizeof(_Float16);   // 25.6 MB

    char* ws = (char*)d_ws;
    size_t off = 0;
    auto alloc = [&](size_t bytes) { char* p = ws + off; off = (off + bytes + 15) & ~(size_t)15; return p; };
    _Float16* xh   = (_Float16*)alloc(hrow);
    _Float16* aggh = (_Float16*)alloc(hrow);
    _Float16* hh   = (_Float16*)alloc(hrow);
    _Float16* zh   = aggh;                  // alias: block reads its rows before writing
    int* hist     = (int*)alloc((size_t)G1 * NB * 4);    // 1.6 MB
    int* totals   = (int*)alloc((size_t)NB * 4);
    int* base     = (int*)alloc((size_t)(NB + 1) * 4);
    int* row_ptr  = (int*)alloc((size_t)(N + 1) * 4);
    int2* tmp     = (int2*)alloc((size_t)E * 8);         // 12.8 MB
    int2* csr     = (int2*)alloc((size_t)E * 8);         // 12.8 MB
    _Float16* w1t = (_Float16*)alloc((size_t)128 * 256 * 2);
    _Float16* w2t = (_Float16*)alloc((size_t)128 * 256 * 2);

    const int* src = ei;
    const int* dst = ei + E;

    const int n8 = N * CH / 8;              // 1.6M

    // --- prep: cast x, transpose weights ---
    cast_kernel<<<(n8 + 255) / 256, 256, 0, stream>>>(x, xh, n8);
    prep_w2_kernel<<<256, 256, 0, stream>>>(w1_rel, w1_root, w2_rel, w2_root, w1t, w2t);

    // --- CSR build (atomic-free bucketed counting sort) ---
    bucket_hist_kernel<<<G1, 256, 0, stream>>>(dst, hist);
    colscan_kernel<<<(NB + 3) / 4, 256, 0, stream>>>(hist, totals);
    scanB_kernel<<<1, 1024, 0, stream>>>(totals, base);
    bucket_scatter_kernel<<<G1, 256, 0, stream>>>(src, dst, ew, hist, base, tmp);
    bucket_finalize_kernel<<<NB, 256, 0, stream>>>(tmp, base, row_ptr, csr, N);

    // --- layer 1 ---
    gather_kernel<<<(N + 3) / 4, 256, 0, stream>>>(xh, row_ptr, csr, aggh, N);
    layer_mfma_kernel<true><<<(N + 63) / 64, 256, 0, stream>>>(aggh, xh, w1t, b1, hh, N);

    // --- layer 2 ---
    gather_kernel<<<(N + 3) / 4, 256, 0, stream>>>(hh, row_ptr, csr, aggh, N);
    layer_mfma_kernel<false><<<(N + 63) / 64, 256, 0, stream>>>(aggh, hh, w2t, b2, zh, N);

    // --- decode ---
    {
        long threads = (long)P * 32;
        decode_kernel<<<(int)((threads + 255) / 256), 256, 0, stream>>>(zh, eli, eli + P, out, P);
    }
}